// Round 8
// baseline (9685.945 us; speedup 1.0000x reference)
//
#include <hip/hip_runtime.h>
#include <math.h>

#define TSTEPS 1024
#define BATCH  512
#define HID    64
#define VOC    29
#define SOS    27
#define MASK29 0x1FFFFFFFu

#define ENC_BLOCKS 256
#define DEC_BLOCKS 256
#define NTHREADS   512

__device__ __forceinline__ float frcp(float x){ return __builtin_amdgcn_rcpf(x); }
__device__ __forceinline__ float sigmf(float x){ return frcp(1.0f + __expf(-x)); }
__device__ __forceinline__ float tanhfast(float x){ return 1.0f - 2.0f*frcp(1.0f + __expf(2.0f*x)); }

// ---------------- Encoder: cross-layer pipelined 2-layer LSTM, 2 rows/block (R4 verbatim) ----
__global__ __attribute__((amdgpu_flat_work_group_size(NTHREADS,NTHREADS), amdgpu_waves_per_eu(2,2)))
void enc_kernel(const float* __restrict__ x,
                const float* __restrict__ Wih0, const float* __restrict__ Whh0,
                const float* __restrict__ bih0, const float* __restrict__ bhh0,
                const float* __restrict__ Wih1, const float* __restrict__ Whh1,
                const float* __restrict__ bih1, const float* __restrict__ bhh1,
                float* __restrict__ h1g, float* __restrict__ c1g)
{
  const int tid = threadIdx.x;
  const int b0  = blockIdx.x * 2;
  const bool g0 = tid < 256;
  const int  r  = g0 ? tid : (tid-256);

  __shared__ __align__(16) float xs[2][32];
  __shared__ __align__(16) float h0s[2][HID], h1s[2][HID];
  __shared__ __align__(16) float gA[2][256], gB[2][256];

  float wh[64], w2[64];
  if (g0){
    #pragma unroll
    for (int k=0;k<64;k++) wh[k] = Whh0[r*64+k];
    #pragma unroll
    for (int k=0;k<29;k++) w2[k] = Wih0[r*29+k];
    #pragma unroll
    for (int k=29;k<64;k++) w2[k] = 0.f;
  } else {
    #pragma unroll
    for (int k=0;k<64;k++){ wh[k] = Whh1[r*64+k]; w2[k] = Wih1[r*64+k]; }
  }
  const float bias = g0 ? (bih0[r]+bhh0[r]) : (bih1[r]+bhh1[r]);

  float creg = 0.f;
  if (tid < 128){ int u=tid>>6,k=tid&63; h0s[u][k]=0.f; h1s[u][k]=0.f; }

  const int pidx = tid - 448;
  const bool pf  = (pidx >= 0) && (pidx < 2*VOC);
  const int prow = pf ? (pidx/VOC) : 0;
  const int pcol = pf ? (pidx%VOC) : 0;
  if (pf) xs[prow][pcol] = x[(size_t)(b0+prow)*VOC + pcol];   // t=0
  __syncthreads();

  for (int t=0;t<=TSTEPS;t++){
    float xv = 0.f;
    if (pf && t+1 < TSTEPS)
      xv = x[(size_t)(t+1)*BATCH*VOC + (size_t)(b0+prow)*VOC + pcol];

    if (g0){
      if (t < TSTEPS){
        #pragma unroll
        for (int u=0;u<2;u++){
          float a0=bias,a1=0.f,a2=0.f,a3=0.f;
          const float4* xv4 = (const float4*)xs[u];
          #pragma unroll
          for (int c=0;c<7;c++){
            float4 q=xv4[c];
            a0=fmaf(q.x,w2[4*c+0],a0); a1=fmaf(q.y,w2[4*c+1],a1);
            a2=fmaf(q.z,w2[4*c+2],a2); a3=fmaf(q.w,w2[4*c+3],a3);
          }
          a0=fmaf(xs[u][28],w2[28],a0);
          const float4* h4=(const float4*)h0s[u];
          #pragma unroll
          for (int c=0;c<16;c++){
            float4 q=h4[c];
            a0=fmaf(q.x,wh[4*c+0],a0); a1=fmaf(q.y,wh[4*c+1],a1);
            a2=fmaf(q.z,wh[4*c+2],a2); a3=fmaf(q.w,wh[4*c+3],a3);
          }
          gA[u][r]=(a0+a1)+(a2+a3);
        }
      }
    } else {
      if (t >= 1){
        #pragma unroll
        for (int u=0;u<2;u++){
          float a0=bias,a1=0.f,a2=0.f,a3=0.f;
          const float4* i4=(const float4*)h0s[u];
          const float4* h4=(const float4*)h1s[u];
          #pragma unroll
          for (int c=0;c<16;c++){
            float4 q=i4[c], w=h4[c];
            a0=fmaf(q.x,w2[4*c+0],a0); a1=fmaf(q.y,w2[4*c+1],a1);
            a2=fmaf(q.z,w2[4*c+2],a2); a3=fmaf(q.w,w2[4*c+3],a3);
            a0=fmaf(w.x,wh[4*c+0],a0); a1=fmaf(w.y,wh[4*c+1],a1);
            a2=fmaf(w.z,wh[4*c+2],a2); a3=fmaf(w.w,wh[4*c+3],a3);
          }
          gB[u][r]=(a0+a1)+(a2+a3);
        }
      }
    }
    __syncthreads();
    if (tid < 128){
      if (t < TSTEPS){
        int u=tid>>6,k=tid&63;
        float ig=gA[u][k],fg=gA[u][64+k],gg=gA[u][128+k],og=gA[u][192+k];
        float c=sigmf(fg)*creg + sigmf(ig)*tanhfast(gg);
        creg=c; h0s[u][k]=sigmf(og)*tanhfast(c);
      }
    } else if (tid < 384){
      if (t >= 1){
        int tt=tid-256,u=tt>>6,k=tt&63;
        float ig=gB[u][k],fg=gB[u][64+k],gg=gB[u][128+k],og=gB[u][192+k];
        float c=sigmf(fg)*creg + sigmf(ig)*tanhfast(gg);
        creg=c; h1s[u][k]=sigmf(og)*tanhfast(c);
      }
    }
    if (pf && t+1 < TSTEPS) xs[prow][pcol] = xv;
    __syncthreads();
  }

  if (tid >= 256 && tid < 384){
    int tt=tid-256,u=tt>>6,k=tt&63;
    h1g[(b0+u)*HID+k]=h1s[u][k];
    c1g[(b0+u)*HID+k]=creg;
  }
}

// ---------------- Decoder: R4 structure + all-wave self-poll, no post-poll sync ----------
__global__ __attribute__((amdgpu_flat_work_group_size(NTHREADS,NTHREADS), amdgpu_waves_per_eu(2,2)))
void dec_kernel(const float* __restrict__ h1gp, const float* __restrict__ c1gp,
                const float* __restrict__ W1ih, const float* __restrict__ W1hh,
                const float* __restrict__ b1ih, const float* __restrict__ b1hh,
                const float* __restrict__ W2ih, const float* __restrict__ W2hh,
                const float* __restrict__ b2ih, const float* __restrict__ b2hh,
                const float* __restrict__ clsW, const float* __restrict__ clsb,
                float* __restrict__ out,
                unsigned long long* __restrict__ lvl1)
{
  const int tid  = threadIdx.x;
  const int r    = tid >> 1;
  const int p    = tid & 1;
  const int b0   = blockIdx.x * 2;
  const unsigned grp = blockIdx.x & 15;   // 16 groups x 16 blocks
  const unsigned idx = blockIdx.x >> 4;   // 0..15

  __shared__ __align__(16) float clsW_s[VOC][68];
  __shared__ __align__(16) float clsb_s[32];
  __shared__ __align__(16) float gl[2][256];
  __shared__ __align__(16) float h1s[2][HID], h2s[2][HID];

  for (int i=tid;i<VOC*HID;i+=NTHREADS) clsW_s[i/HID][i%HID]=clsW[i];
  if (tid<VOC) clsb_s[tid]=clsb[tid];

  float wi1c[15], w1h[32], w2i[32], w2h[32];
  #pragma unroll
  for (int j=0;j<15;j++) wi1c[j] = (p && j==14) ? 0.f : W1ih[r*VOC + p*15 + j];
  #pragma unroll
  for (int j=0;j<32;j++){
    w1h[j]=W1hh[r*HID+32*p+j];
    w2i[j]=W2ih[r*HID+32*p+j];
    w2h[j]=W2hh[r*HID+32*p+j];
  }
  const float bs1 = p?0.f:(b1ih[r]+b1hh[r]);
  const float bs2 = p?0.f:(b2ih[r]+b2hh[r]);

  float c1reg=0.f, c2reg=0.f;
  if (tid<128){
    int u=tid>>6,k=tid&63;
    h1s[u][k]=h1gp[(b0+u)*HID+k];
    c1reg    =c1gp[(b0+u)*HID+k];
    h2s[u][k]=0.f;
  }
  __syncthreads();

  float hd1[2];
  #pragma unroll
  for (int u=0;u<2;u++){
    float a0=0.f,a1=0.f,a2=0.f,a3=0.f;
    const float4* hv=(const float4*)&h1s[u][32*p];
    #pragma unroll
    for (int c=0;c<8;c++){
      float4 q=hv[c];
      a0=fmaf(q.x,w1h[4*c+0],a0); a1=fmaf(q.y,w1h[4*c+1],a1);
      a2=fmaf(q.z,w1h[4*c+2],a2); a3=fmaf(q.w,w1h[4*c+3],a3);
    }
    hd1[u]=(a0+a1)+(a2+a3);
  }

  unsigned mask = 1u<<SOS;

  for (int s=0;s<TSTEPS;s++){
    // ---- gate1 = input-term(mask) + hd1 (pure registers) ----
    #pragma unroll
    for (int u=0;u<2;u++){
      float it = bs1;
      #pragma unroll
      for (int j=0;j<15;j++)
        it += ((mask>>(p*15+j))&1u) ? wi1c[j] : 0.f;
      float v = it + hd1[u];
      v += __shfl_xor(v,1);
      if (!p) gl[u][r] = v;
    }
    __syncthreads();
    if (tid<128){
      int u=tid>>6,k=tid&63;
      float ig=gl[u][k],fg=gl[u][64+k],gg=gl[u][128+k],og=gl[u][192+k];
      float c=sigmf(fg)*c1reg+sigmf(ig)*tanhfast(gg);
      c1reg=c; h1s[u][k]=sigmf(og)*tanhfast(c);
    }
    __syncthreads();
    // ---- gate2 ----
    #pragma unroll
    for (int u=0;u<2;u++){
      float a0=bs2,a1=0.f,a2=0.f,a3=0.f;
      const float4* iv=(const float4*)&h1s[u][32*p];
      const float4* hv=(const float4*)&h2s[u][32*p];
      #pragma unroll
      for (int c=0;c<8;c++){
        float4 q=iv[c], w=hv[c];
        a0=fmaf(q.x,w2i[4*c+0],a0); a1=fmaf(q.y,w2i[4*c+1],a1);
        a2=fmaf(q.z,w2i[4*c+2],a2); a3=fmaf(q.w,w2i[4*c+3],a3);
        a0=fmaf(w.x,w2h[4*c+0],a0); a1=fmaf(w.y,w2h[4*c+1],a1);
        a2=fmaf(w.z,w2h[4*c+2],a2); a3=fmaf(w.w,w2h[4*c+3],a3);
      }
      float v=(a0+a1)+(a2+a3);
      v += __shfl_xor(v,1);
      if (!p) gl[u][r]=v;
    }
    __syncthreads();
    if (tid<128){
      int u=tid>>6,k=tid&63;
      float ig=gl[u][k],fg=gl[u][64+k],gg=gl[u][128+k],og=gl[u][192+k];
      float c=sigmf(fg)*c2reg+sigmf(ig)*tanhfast(gg);
      c2reg=c; h2s[u][k]=sigmf(og)*tanhfast(c);
    }
    __syncthreads();
    // ---- classifier + argmax + RMW (wave0) ----
    if (tid<64){
      int row2=tid>>5, v2=tid&31;
      float pv=-INFINITY;
      if (v2<VOC){
        float a0=clsb_s[v2],a1=0.f,a2=0.f,a3=0.f;
        const float4* h4=(const float4*)h2s[row2];
        #pragma unroll
        for (int c=0;c<16;c++){
          float4 q=h4[c];
          a0=fmaf(q.x,clsW_s[v2][4*c+0],a0); a1=fmaf(q.y,clsW_s[v2][4*c+1],a1);
          a2=fmaf(q.z,clsW_s[v2][4*c+2],a2); a3=fmaf(q.w,clsW_s[v2][4*c+3],a3);
        }
        pv=(a0+a1)+(a2+a3);
        out[((size_t)s*BATCH + (size_t)(b0+row2))*VOC + v2]=pv;
      }
      int ix=v2;
      #pragma unroll
      for (int off=16; off>0; off>>=1){
        float ov=__shfl_xor(pv,off);
        int   oi=__shfl_xor(ix,off);
        if (ov>pv || (ov==pv && oi<ix)){ pv=ov; ix=oi; }
      }
      unsigned bit = 1u<<ix;
      unsigned mb  = bit | __shfl_xor(bit,32);
      if (tid==0 && s+1<TSTEPS)
        __hip_atomic_fetch_or(&lvl1[(size_t)grp*TSTEPS+s],
                              (unsigned long long)mb | (1ULL<<(32+idx)),
                              __ATOMIC_RELAXED, __HIP_MEMORY_SCOPE_AGENT);
    }
    // ---- hd1 for next step (reads h1s written this step; next write is after sync1(s+1)) ----
    #pragma unroll
    for (int u=0;u<2;u++){
      float a0=0.f,a1=0.f,a2=0.f,a3=0.f;
      const float4* hv=(const float4*)&h1s[u][32*p];
      #pragma unroll
      for (int c=0;c<8;c++){
        float4 q=hv[c];
        a0=fmaf(q.x,w1h[4*c+0],a0); a1=fmaf(q.y,w1h[4*c+1],a1);
        a2=fmaf(q.z,w1h[4*c+2],a2); a3=fmaf(q.w,w1h[4*c+3],a3);
      }
      hd1[u]=(a0+a1)+(a2+a3);
    }
    // ---- all-wave independent poll; no block barrier needed afterwards ----
    if (s+1<TSTEPS){
      const int lane = tid & 63;
      unsigned m;
      while (true){
        unsigned long long u64 = 0;
        if (lane<16)
          u64 = __hip_atomic_load(&lvl1[(size_t)lane*TSTEPS+s],
                                  __ATOMIC_RELAXED, __HIP_MEMORY_SCOPE_AGENT);
        bool ok = (lane>=16) || ((unsigned)(u64>>32) == 0xFFFFu);
        if (__ballot(ok) == ~0ull){
          m = (lane<16) ? ((unsigned)u64 & MASK29) : 0u;
          m |= __shfl_xor(m,1); m |= __shfl_xor(m,2);
          m |= __shfl_xor(m,4); m |= __shfl_xor(m,8);
          m = __shfl(m,0);
          break;
        }
      }
      mask = m;
    }
  }
}

extern "C" void kernel_launch(void* const* d_in, const int* in_sizes, int n_in,
                              void* d_out, int out_size, void* d_ws, size_t ws_size,
                              hipStream_t stream)
{
  const float* x     = (const float*)d_in[0];
  const float* eWih0 = (const float*)d_in[1];
  const float* eWhh0 = (const float*)d_in[2];
  const float* ebih0 = (const float*)d_in[3];
  const float* ebhh0 = (const float*)d_in[4];
  const float* eWih1 = (const float*)d_in[5];
  const float* eWhh1 = (const float*)d_in[6];
  const float* ebih1 = (const float*)d_in[7];
  const float* ebhh1 = (const float*)d_in[8];
  const float* d1Wih = (const float*)d_in[9];
  const float* d1Whh = (const float*)d_in[10];
  const float* d1bih = (const float*)d_in[11];
  const float* d1bhh = (const float*)d_in[12];
  const float* d2Wih = (const float*)d_in[13];
  const float* d2Whh = (const float*)d_in[14];
  const float* d2bih = (const float*)d_in[15];
  const float* d2bhh = (const float*)d_in[16];
  const float* clsW  = (const float*)d_in[17];
  const float* clsb  = (const float*)d_in[18];
  float* out = (float*)d_out;

  float* h1g = (float*)d_ws;
  float* c1g = h1g + BATCH*HID;
  unsigned long long* lvl1 = (unsigned long long*)((char*)d_ws + (size_t)(2*BATCH*HID)*sizeof(float));

  hipMemsetAsync(lvl1, 0, 16*TSTEPS*sizeof(unsigned long long), stream);

  enc_kernel<<<ENC_BLOCKS, NTHREADS, 0, stream>>>(
      x, eWih0,eWhh0,ebih0,ebhh0, eWih1,eWhh1,ebih1,ebhh1, h1g,c1g);

  void* args[] = { (void*)&h1g, (void*)&c1g,
                   (void*)&d1Wih,(void*)&d1Whh,(void*)&d1bih,(void*)&d1bhh,
                   (void*)&d2Wih,(void*)&d2Whh,(void*)&d2bih,(void*)&d2bhh,
                   (void*)&clsW,(void*)&clsb,(void*)&out,(void*)&lvl1 };
  hipLaunchCooperativeKernel((void*)dec_kernel, dim3(DEC_BLOCKS), dim3(NTHREADS),
                             args, 0, stream);
}

// Round 9
// 5904.656 us; speedup vs baseline: 1.6404x; 1.6404x over previous
//
#include <hip/hip_runtime.h>
#include <math.h>

#define TSTEPS 1024
#define BATCH  512
#define HID    64
#define VOC    29
#define SOS    27
#define MASK29 0x1FFFFFFFu

#define ENC_BLOCKS 256
#define DEC_BLOCKS 256
#define NTHREADS   512

__device__ __forceinline__ float frcp(float x){ return __builtin_amdgcn_rcpf(x); }
__device__ __forceinline__ float sigmf(float x){ return frcp(1.0f + __expf(-x)); }
__device__ __forceinline__ float tanhfast(float x){ return 1.0f - 2.0f*frcp(1.0f + __expf(2.0f*x)); }

// ---------------- Encoder: cross-layer pipelined 2-layer LSTM, 2 rows/block (R4 verbatim) ----
__global__ __attribute__((amdgpu_flat_work_group_size(NTHREADS,NTHREADS), amdgpu_waves_per_eu(2,2)))
void enc_kernel(const float* __restrict__ x,
                const float* __restrict__ Wih0, const float* __restrict__ Whh0,
                const float* __restrict__ bih0, const float* __restrict__ bhh0,
                const float* __restrict__ Wih1, const float* __restrict__ Whh1,
                const float* __restrict__ bih1, const float* __restrict__ bhh1,
                float* __restrict__ h1g, float* __restrict__ c1g)
{
  const int tid = threadIdx.x;
  const int b0  = blockIdx.x * 2;
  const bool g0 = tid < 256;
  const int  r  = g0 ? tid : (tid-256);

  __shared__ __align__(16) float xs[2][32];
  __shared__ __align__(16) float h0s[2][HID], h1s[2][HID];
  __shared__ __align__(16) float gA[2][256], gB[2][256];

  float wh[64], w2[64];
  if (g0){
    #pragma unroll
    for (int k=0;k<64;k++) wh[k] = Whh0[r*64+k];
    #pragma unroll
    for (int k=0;k<29;k++) w2[k] = Wih0[r*29+k];
    #pragma unroll
    for (int k=29;k<64;k++) w2[k] = 0.f;
  } else {
    #pragma unroll
    for (int k=0;k<64;k++){ wh[k] = Whh1[r*64+k]; w2[k] = Wih1[r*64+k]; }
  }
  const float bias = g0 ? (bih0[r]+bhh0[r]) : (bih1[r]+bhh1[r]);

  float creg = 0.f;
  if (tid < 128){ int u=tid>>6,k=tid&63; h0s[u][k]=0.f; h1s[u][k]=0.f; }

  const int pidx = tid - 448;
  const bool pf  = (pidx >= 0) && (pidx < 2*VOC);
  const int prow = pf ? (pidx/VOC) : 0;
  const int pcol = pf ? (pidx%VOC) : 0;
  if (pf) xs[prow][pcol] = x[(size_t)(b0+prow)*VOC + pcol];   // t=0
  __syncthreads();

  for (int t=0;t<=TSTEPS;t++){
    float xv = 0.f;
    if (pf && t+1 < TSTEPS)
      xv = x[(size_t)(t+1)*BATCH*VOC + (size_t)(b0+prow)*VOC + pcol];

    if (g0){
      if (t < TSTEPS){
        #pragma unroll
        for (int u=0;u<2;u++){
          float a0=bias,a1=0.f,a2=0.f,a3=0.f;
          const float4* xv4 = (const float4*)xs[u];
          #pragma unroll
          for (int c=0;c<7;c++){
            float4 q=xv4[c];
            a0=fmaf(q.x,w2[4*c+0],a0); a1=fmaf(q.y,w2[4*c+1],a1);
            a2=fmaf(q.z,w2[4*c+2],a2); a3=fmaf(q.w,w2[4*c+3],a3);
          }
          a0=fmaf(xs[u][28],w2[28],a0);
          const float4* h4=(const float4*)h0s[u];
          #pragma unroll
          for (int c=0;c<16;c++){
            float4 q=h4[c];
            a0=fmaf(q.x,wh[4*c+0],a0); a1=fmaf(q.y,wh[4*c+1],a1);
            a2=fmaf(q.z,wh[4*c+2],a2); a3=fmaf(q.w,wh[4*c+3],a3);
          }
          gA[u][r]=(a0+a1)+(a2+a3);
        }
      }
    } else {
      if (t >= 1){
        #pragma unroll
        for (int u=0;u<2;u++){
          float a0=bias,a1=0.f,a2=0.f,a3=0.f;
          const float4* i4=(const float4*)h0s[u];
          const float4* h4=(const float4*)h1s[u];
          #pragma unroll
          for (int c=0;c<16;c++){
            float4 q=i4[c], w=h4[c];
            a0=fmaf(q.x,w2[4*c+0],a0); a1=fmaf(q.y,w2[4*c+1],a1);
            a2=fmaf(q.z,w2[4*c+2],a2); a3=fmaf(q.w,w2[4*c+3],a3);
            a0=fmaf(w.x,wh[4*c+0],a0); a1=fmaf(w.y,wh[4*c+1],a1);
            a2=fmaf(w.z,wh[4*c+2],a2); a3=fmaf(w.w,wh[4*c+3],a3);
          }
          gB[u][r]=(a0+a1)+(a2+a3);
        }
      }
    }
    __syncthreads();
    if (tid < 128){
      if (t < TSTEPS){
        int u=tid>>6,k=tid&63;
        float ig=gA[u][k],fg=gA[u][64+k],gg=gA[u][128+k],og=gA[u][192+k];
        float c=sigmf(fg)*creg + sigmf(ig)*tanhfast(gg);
        creg=c; h0s[u][k]=sigmf(og)*tanhfast(c);
      }
    } else if (tid < 384){
      if (t >= 1){
        int tt=tid-256,u=tt>>6,k=tt&63;
        float ig=gB[u][k],fg=gB[u][64+k],gg=gB[u][128+k],og=gB[u][192+k];
        float c=sigmf(fg)*creg + sigmf(ig)*tanhfast(gg);
        creg=c; h1s[u][k]=sigmf(og)*tanhfast(c);
      }
    }
    if (pf && t+1 < TSTEPS) xs[prow][pcol] = xv;
    __syncthreads();
  }

  if (tid >= 256 && tid < 384){
    int tt=tid-256,u=tt>>6,k=tt&63;
    h1g[(b0+u)*HID+k]=h1s[u][k];
    c1g[(b0+u)*HID+k]=creg;
  }
}

// ---------------- Decoder: R4 structure + per-block slot-store barrier (no RMW) ----------
// slots[parity][block]: value = mask | tag<<30, tag = ((s>>1)&1)+1. Skew<=1 step, so a
// same-parity slot can only hold s or s-2 -> 1-bit tag distinguishes; 0 = never-written.
__global__ __attribute__((amdgpu_flat_work_group_size(NTHREADS,NTHREADS), amdgpu_waves_per_eu(2,2)))
void dec_kernel(const float* __restrict__ h1gp, const float* __restrict__ c1gp,
                const float* __restrict__ W1ih, const float* __restrict__ W1hh,
                const float* __restrict__ b1ih, const float* __restrict__ b1hh,
                const float* __restrict__ W2ih, const float* __restrict__ W2hh,
                const float* __restrict__ b2ih, const float* __restrict__ b2hh,
                const float* __restrict__ clsW, const float* __restrict__ clsb,
                float* __restrict__ out,
                unsigned* __restrict__ slots)
{
  const int tid  = threadIdx.x;
  const int r    = tid >> 1;
  const int p    = tid & 1;
  const int b0   = blockIdx.x * 2;

  __shared__ __align__(16) float clsW_s[VOC][68];
  __shared__ __align__(16) float clsb_s[32];
  __shared__ __align__(16) float gl[2][256];
  __shared__ __align__(16) float h1s[2][HID], h2s[2][HID];
  __shared__ unsigned maskLDS;

  for (int i=tid;i<VOC*HID;i+=NTHREADS) clsW_s[i/HID][i%HID]=clsW[i];
  if (tid<VOC) clsb_s[tid]=clsb[tid];

  float wi1c[15], w1h[32], w2i[32], w2h[32];
  #pragma unroll
  for (int j=0;j<15;j++) wi1c[j] = (p && j==14) ? 0.f : W1ih[r*VOC + p*15 + j];
  #pragma unroll
  for (int j=0;j<32;j++){
    w1h[j]=W1hh[r*HID+32*p+j];
    w2i[j]=W2ih[r*HID+32*p+j];
    w2h[j]=W2hh[r*HID+32*p+j];
  }
  const float bs1 = p?0.f:(b1ih[r]+b1hh[r]);
  const float bs2 = p?0.f:(b2ih[r]+b2hh[r]);

  float c1reg=0.f, c2reg=0.f;
  if (tid<128){
    int u=tid>>6,k=tid&63;
    h1s[u][k]=h1gp[(b0+u)*HID+k];
    c1reg    =c1gp[(b0+u)*HID+k];
    h2s[u][k]=0.f;
  }
  __syncthreads();

  float hd1[2];
  #pragma unroll
  for (int u=0;u<2;u++){
    float a0=0.f,a1=0.f,a2=0.f,a3=0.f;
    const float4* hv=(const float4*)&h1s[u][32*p];
    #pragma unroll
    for (int c=0;c<8;c++){
      float4 q=hv[c];
      a0=fmaf(q.x,w1h[4*c+0],a0); a1=fmaf(q.y,w1h[4*c+1],a1);
      a2=fmaf(q.z,w1h[4*c+2],a2); a3=fmaf(q.w,w1h[4*c+3],a3);
    }
    hd1[u]=(a0+a1)+(a2+a3);
  }

  unsigned mask = 1u<<SOS;

  for (int s=0;s<TSTEPS;s++){
    // ---- gate1 = input-term(mask) + hd1 (pure registers) ----
    #pragma unroll
    for (int u=0;u<2;u++){
      float it = bs1;
      #pragma unroll
      for (int j=0;j<15;j++)
        it += ((mask>>(p*15+j))&1u) ? wi1c[j] : 0.f;
      float v = it + hd1[u];
      v += __shfl_xor(v,1);
      if (!p) gl[u][r] = v;
    }
    __syncthreads();
    if (tid<128){
      int u=tid>>6,k=tid&63;
      float ig=gl[u][k],fg=gl[u][64+k],gg=gl[u][128+k],og=gl[u][192+k];
      float c=sigmf(fg)*c1reg+sigmf(ig)*tanhfast(gg);
      c1reg=c; h1s[u][k]=sigmf(og)*tanhfast(c);
    }
    __syncthreads();
    // ---- gate2 ----
    #pragma unroll
    for (int u=0;u<2;u++){
      float a0=bs2,a1=0.f,a2=0.f,a3=0.f;
      const float4* iv=(const float4*)&h1s[u][32*p];
      const float4* hv=(const float4*)&h2s[u][32*p];
      #pragma unroll
      for (int c=0;c<8;c++){
        float4 q=iv[c], w=hv[c];
        a0=fmaf(q.x,w2i[4*c+0],a0); a1=fmaf(q.y,w2i[4*c+1],a1);
        a2=fmaf(q.z,w2i[4*c+2],a2); a3=fmaf(q.w,w2i[4*c+3],a3);
        a0=fmaf(w.x,w2h[4*c+0],a0); a1=fmaf(w.y,w2h[4*c+1],a1);
        a2=fmaf(w.z,w2h[4*c+2],a2); a3=fmaf(w.w,w2h[4*c+3],a3);
      }
      float v=(a0+a1)+(a2+a3);
      v += __shfl_xor(v,1);
      if (!p) gl[u][r]=v;
    }
    __syncthreads();
    if (tid<128){
      int u=tid>>6,k=tid&63;
      float ig=gl[u][k],fg=gl[u][64+k],gg=gl[u][128+k],og=gl[u][192+k];
      float c=sigmf(fg)*c2reg+sigmf(ig)*tanhfast(gg);
      c2reg=c; h2s[u][k]=sigmf(og)*tanhfast(c);
    }
    __syncthreads();
    // ---- classifier + argmax; PUBLISH first, then out-store (wave0) ----
    if (tid<64){
      int row2=tid>>5, v2=tid&31;
      float pv=-INFINITY;
      if (v2<VOC){
        float a0=clsb_s[v2],a1=0.f,a2=0.f,a3=0.f;
        const float4* h4=(const float4*)h2s[row2];
        #pragma unroll
        for (int c=0;c<16;c++){
          float4 q=h4[c];
          a0=fmaf(q.x,clsW_s[v2][4*c+0],a0); a1=fmaf(q.y,clsW_s[v2][4*c+1],a1);
          a2=fmaf(q.z,clsW_s[v2][4*c+2],a2); a3=fmaf(q.w,clsW_s[v2][4*c+3],a3);
        }
        pv=(a0+a1)+(a2+a3);
      }
      float rv=pv; int ix=v2;
      #pragma unroll
      for (int off=16; off>0; off>>=1){
        float ov=__shfl_xor(rv,off);
        int   oi=__shfl_xor(ix,off);
        if (ov>rv || (ov==rv && oi<ix)){ rv=ov; ix=oi; }
      }
      unsigned bit = 1u<<ix;
      unsigned mb  = bit | __shfl_xor(bit,32);
      if (tid==0 && s+1<TSTEPS){
        unsigned tag = (((unsigned)(s>>1)&1u)+1u)<<30;
        __hip_atomic_store(&slots[(unsigned)(s&1)*DEC_BLOCKS + blockIdx.x], mb|tag,
                           __ATOMIC_RELAXED, __HIP_MEMORY_SCOPE_AGENT);
      }
      if (v2<VOC)
        out[((size_t)s*BATCH + (size_t)(b0+row2))*VOC + v2]=pv;
    }
    // ---- hd1 for next step (reads h1s written this step; next write after sync1(s+1)) ----
    #pragma unroll
    for (int u=0;u<2;u++){
      float a0=0.f,a1=0.f,a2=0.f,a3=0.f;
      const float4* hv=(const float4*)&h1s[u][32*p];
      #pragma unroll
      for (int c=0;c<8;c++){
        float4 q=hv[c];
        a0=fmaf(q.x,w1h[4*c+0],a0); a1=fmaf(q.y,w1h[4*c+1],a1);
        a2=fmaf(q.z,w1h[4*c+2],a2); a3=fmaf(q.w,w1h[4*c+3],a3);
      }
      hd1[u]=(a0+a1)+(a2+a3);
    }
    // ---- wave0-only slot poll; others park at the barrier ----
    if (s+1<TSTEPS){
      if (tid<64){
        const unsigned tg = ((unsigned)(s>>1)&1u)+1u;
        const unsigned* base = slots + (unsigned)(s&1)*DEC_BLOCKS + tid*4;
        while (true){
          unsigned w0=__hip_atomic_load(base+0,__ATOMIC_RELAXED,__HIP_MEMORY_SCOPE_AGENT);
          unsigned w1=__hip_atomic_load(base+1,__ATOMIC_RELAXED,__HIP_MEMORY_SCOPE_AGENT);
          unsigned w2=__hip_atomic_load(base+2,__ATOMIC_RELAXED,__HIP_MEMORY_SCOPE_AGENT);
          unsigned w3=__hip_atomic_load(base+3,__ATOMIC_RELAXED,__HIP_MEMORY_SCOPE_AGENT);
          bool ok = ((w0>>30)==tg) && ((w1>>30)==tg) && ((w2>>30)==tg) && ((w3>>30)==tg);
          if (__ballot(ok) == ~0ull){
            unsigned m = (w0|w1|w2|w3) & MASK29;
            m |= __shfl_xor(m,1);  m |= __shfl_xor(m,2);
            m |= __shfl_xor(m,4);  m |= __shfl_xor(m,8);
            m |= __shfl_xor(m,16); m |= __shfl_xor(m,32);
            if (tid==0) maskLDS = m;
            break;
          }
        }
      }
      __syncthreads();
      mask = maskLDS;
    }
  }
}

extern "C" void kernel_launch(void* const* d_in, const int* in_sizes, int n_in,
                              void* d_out, int out_size, void* d_ws, size_t ws_size,
                              hipStream_t stream)
{
  const float* x     = (const float*)d_in[0];
  const float* eWih0 = (const float*)d_in[1];
  const float* eWhh0 = (const float*)d_in[2];
  const float* ebih0 = (const float*)d_in[3];
  const float* ebhh0 = (const float*)d_in[4];
  const float* eWih1 = (const float*)d_in[5];
  const float* eWhh1 = (const float*)d_in[6];
  const float* ebih1 = (const float*)d_in[7];
  const float* ebhh1 = (const float*)d_in[8];
  const float* d1Wih = (const float*)d_in[9];
  const float* d1Whh = (const float*)d_in[10];
  const float* d1bih = (const float*)d_in[11];
  const float* d1bhh = (const float*)d_in[12];
  const float* d2Wih = (const float*)d_in[13];
  const float* d2Whh = (const float*)d_in[14];
  const float* d2bih = (const float*)d_in[15];
  const float* d2bhh = (const float*)d_in[16];
  const float* clsW  = (const float*)d_in[17];
  const float* clsb  = (const float*)d_in[18];
  float* out = (float*)d_out;

  float* h1g = (float*)d_ws;
  float* c1g = h1g + BATCH*HID;
  unsigned* slots = (unsigned*)((char*)d_ws + (size_t)(2*BATCH*HID)*sizeof(float));

  hipMemsetAsync(slots, 0, 2*DEC_BLOCKS*sizeof(unsigned), stream);

  enc_kernel<<<ENC_BLOCKS, NTHREADS, 0, stream>>>(
      x, eWih0,eWhh0,ebih0,ebhh0, eWih1,eWhh1,ebih1,ebhh1, h1g,c1g);

  void* args[] = { (void*)&h1g, (void*)&c1g,
                   (void*)&d1Wih,(void*)&d1Whh,(void*)&d1bih,(void*)&d1bhh,
                   (void*)&d2Wih,(void*)&d2Whh,(void*)&d2bih,(void*)&d2bhh,
                   (void*)&clsW,(void*)&clsb,(void*)&out,(void*)&slots };
  hipLaunchCooperativeKernel((void*)dec_kernel, dim3(DEC_BLOCKS), dim3(NTHREADS),
                             args, 0, stream);
}